// Round 8
// baseline (930.270 us; speedup 1.0000x reference)
//
#include <hip/hip_runtime.h>

typedef __bf16 bf16x8 __attribute__((ext_vector_type(8)));
typedef __bf16 bf16x4 __attribute__((ext_vector_type(4)));
typedef float f32x4 __attribute__((ext_vector_type(4)));
typedef float f32x16 __attribute__((ext_vector_type(16)));

#define MFMA16(a, b, c) __builtin_amdgcn_mfma_f32_16x16x32_bf16((a), (b), (c), 0, 0, 0)
#define MFMA32(a, b, c) __builtin_amdgcn_mfma_f32_32x32x16_bf16((a), (b), (c), 0, 0, 0)

static constexpr int SEQ = 4096;
static constexpr int DIM = 512;

typedef __attribute__((address_space(3))) void lds_void;
typedef __attribute__((address_space(1))) const void gbl_void;

__device__ __forceinline__ void glds16(const void* g, void* l) {
    __builtin_amdgcn_global_load_lds((gbl_void*)g, (lds_void*)l, 16, 0, 0);
}

__device__ __forceinline__ bf16x8 cvt8f(const float* __restrict__ p) {
    float4 f0 = *(const float4*)p;
    float4 f1 = *(const float4*)(p + 4);
    bf16x8 v;
    v[0] = (__bf16)f0.x; v[1] = (__bf16)f0.y; v[2] = (__bf16)f0.z; v[3] = (__bf16)f0.w;
    v[4] = (__bf16)f1.x; v[5] = (__bf16)f1.y; v[6] = (__bf16)f1.z; v[7] = (__bf16)f1.w;
    return v;
}

// ---------------------------------------------------------------------------
// Weight fp32 -> bf16 converter
// ---------------------------------------------------------------------------
__global__ __launch_bounds__(256)
void convert_w(const float* __restrict__ wq, const float* __restrict__ wk,
               const float* __restrict__ wv, const float* __restrict__ wo,
               __bf16* __restrict__ out)
{
    const int z = blockIdx.y;
    const float* src = (z == 0) ? wq : (z == 1) ? wk : (z == 2) ? wv : wo;
    __bf16* dst = out + (size_t)z * DIM * DIM;
    const int i = (blockIdx.x * 256 + threadIdx.x) * 8;
    *(bf16x8*)(dst + i) = cvt8f(src + i);
}

// ---------------------------------------------------------------------------
// Batched QKV projection GEMM (proven R3): z in {0,1,2} -> Qp, Kp, Vt^T.
// ---------------------------------------------------------------------------
__global__ __launch_bounds__(256, 3)
void gemm_qkv(const float* __restrict__ Aq, const float* __restrict__ Ak,
              const float* __restrict__ Av, const __bf16* __restrict__ Wb,
              __bf16* __restrict__ Qp, __bf16* __restrict__ Kp,
              __bf16* __restrict__ Vtp)
{
    const int z = blockIdx.z;
    const float* Ap = (z == 0) ? Aq : (z == 1) ? Ak : Av;
    const __bf16* Bp = Wb + (size_t)z * DIM * DIM;
    __bf16* Cp = (z == 0) ? Qp : (z == 1) ? Kp : Vtp;

    __shared__ __align__(16) char smem[128 * 132 * 2];   // 33792 B
    __bf16* As = (__bf16*)smem;                // [128][64]
    __bf16* Bs = (__bf16*)(smem + 16384);      // [128][64]

    const int tid  = threadIdx.x;
    const int wave = tid >> 6;
    const int lane = tid & 63;
    const int quad = lane >> 4;
    const int l16  = lane & 15;
    const int m0 = blockIdx.x * 128;
    const int n0 = blockIdx.y * 128;
    const int wm = (wave >> 1) * 64;
    const int wn = (wave & 1) * 64;

    f32x4 acc[4][4] = {};

    for (int k0 = 0; k0 < DIM; k0 += 64) {
        #pragma unroll
        for (int i = 0; i < 4; i++) {
            const int j = wave * 4 + i;
            const int t = j * 64 + lane;
            const int row = t >> 3, c8 = t & 7;
            glds16(Bp + (size_t)(n0 + row) * DIM + k0 + c8 * 8, &Bs[j * 512]);
            *(bf16x8*)&As[t * 8] =
                cvt8f(Ap + (size_t)(m0 + row) * DIM + k0 + c8 * 8);
        }
        __syncthreads();
        #pragma unroll
        for (int kk = 0; kk < 2; kk++) {
            bf16x8 af[4], bg[4];
            #pragma unroll
            for (int mt = 0; mt < 4; mt++)
                af[mt] = *(const bf16x8*)&As[(wm + mt * 16 + l16) * 64 + kk * 32 + quad * 8];
            #pragma unroll
            for (int nt = 0; nt < 4; nt++)
                bg[nt] = *(const bf16x8*)&Bs[(wn + nt * 16 + l16) * 64 + kk * 32 + quad * 8];
            #pragma unroll
            for (int mt = 0; mt < 4; mt++)
                #pragma unroll
                for (int nt = 0; nt < 4; nt++)
                    acc[mt][nt] = MFMA16(af[mt], bg[nt], acc[mt][nt]);
        }
        __syncthreads();
    }

    if (z < 2) {
        #pragma unroll
        for (int mt = 0; mt < 4; mt++)
            #pragma unroll
            for (int nt = 0; nt < 4; nt++)
                #pragma unroll
                for (int r = 0; r < 4; r++)
                    Cp[(size_t)(m0 + wm + mt * 16 + quad * 4 + r) * DIM
                       + n0 + wn + nt * 16 + l16] = (__bf16)acc[mt][nt][r];
    } else {
        // transpose epilogue: Vt[nb][d][s]
        __bf16* Tt = (__bf16*)smem;            // [128][132]
        __syncthreads();
        #pragma unroll
        for (int mt = 0; mt < 4; mt++)
            #pragma unroll
            for (int nt = 0; nt < 4; nt++)
                #pragma unroll
                for (int r = 0; r < 4; r++)
                    Tt[(wm + mt * 16 + quad * 4 + r) * 132 + wn + nt * 16 + l16]
                        = (__bf16)acc[mt][nt][r];
        __syncthreads();
        const int nb  = m0 >> 12;
        const int s0m = m0 & 4095;
        const int d   = tid >> 1;
        const int sh  = (tid & 1) * 64;
        __bf16* dst = Cp + (size_t)nb * DIM * SEQ + (size_t)(n0 + d) * SEQ + s0m + sh;
        #pragma unroll
        for (int i = 0; i < 8; i++) {
            bf16x8 vv;
            #pragma unroll
            for (int e = 0; e < 8; e++) vv[e] = Tt[(sh + i * 8 + e) * 132 + d];
            *(bf16x8*)(dst + i * 8) = vv;
        }
    }
}

// ---------------------------------------------------------------------------
// Output GEMM: C(fp32) = A(bf16) @ Wo(bf16)^T + bias (m97 structure)
// ---------------------------------------------------------------------------
__global__ __launch_bounds__(256, 3)
void gemm_out(const __bf16* __restrict__ Ap, const __bf16* __restrict__ Bp,
              float* __restrict__ Cp, const float* __restrict__ bias)
{
    __shared__ __align__(16) __bf16 As[128 * 64];
    __shared__ __align__(16) __bf16 Bs[128 * 64];
    const int tid  = threadIdx.x;
    const int wave = tid >> 6;
    const int lane = tid & 63;
    const int quad = lane >> 4;
    const int l16  = lane & 15;
    const int m0 = blockIdx.x * 128;
    const int n0 = blockIdx.y * 128;
    const int wm = (wave >> 1) * 64;
    const int wn = (wave & 1) * 64;

    f32x4 acc[4][4] = {};

    for (int k0 = 0; k0 < DIM; k0 += 64) {
        #pragma unroll
        for (int i = 0; i < 4; i++) {
            const int j = wave * 4 + i;
            const int c = j * 64 + lane;
            const int row = c >> 3, c8 = c & 7;
            glds16(Ap + (size_t)(m0 + row) * DIM + k0 + c8 * 8, &As[j * 512]);
            glds16(Bp + (size_t)(n0 + row) * DIM + k0 + c8 * 8, &Bs[j * 512]);
        }
        __syncthreads();
        #pragma unroll
        for (int kk = 0; kk < 2; kk++) {
            bf16x8 af[4], bg[4];
            #pragma unroll
            for (int mt = 0; mt < 4; mt++)
                af[mt] = *(const bf16x8*)&As[(wm + mt * 16 + l16) * 64 + kk * 32 + quad * 8];
            #pragma unroll
            for (int nt = 0; nt < 4; nt++)
                bg[nt] = *(const bf16x8*)&Bs[(wn + nt * 16 + l16) * 64 + kk * 32 + quad * 8];
            #pragma unroll
            for (int mt = 0; mt < 4; mt++)
                #pragma unroll
                for (int nt = 0; nt < 4; nt++)
                    acc[mt][nt] = MFMA16(af[mt], bg[nt], acc[mt][nt]);
        }
        __syncthreads();
    }
    #pragma unroll
    for (int mt = 0; mt < 4; mt++)
        #pragma unroll
        for (int nt = 0; nt < 4; nt++)
            #pragma unroll
            for (int r = 0; r < 4; r++) {
                const int col = n0 + wn + nt * 16 + l16;
                Cp[(size_t)(m0 + wm + mt * 16 + quad * 4 + r) * DIM + col]
                    = acc[mt][nt][r] + bias[col];
            }
}

// ---------------------------------------------------------------------------
// Flash attention v14 — v13 data path (K/V global->reg, Q/P in LDS with
// rotation pitches, 3 barriers/j) at DOUBLE occupancy: 32 q-rows/block,
// 512 blocks, 2 blocks/CU -> 4 waves/SIMD. All three ~325us kernels shared
// 2 waves/SIMD with every pipe <25% busy => latency-bound; TLP is the fix.
// Per-wave state halves (s1/o01/o11/mk1 deleted, ~48 acc VGPR) to fit the
// 128-VGPR/4-wave budget. 2-buffer K/V prefetch. LDS 52.4 KB/block.
// ---------------------------------------------------------------------------
#define MKC(v, r4) ((r4) == 0 ? (v).x : (r4) == 1 ? (v).y : (r4) == 2 ? (v).z : (v).w)
#define WAITLGKM() asm volatile("s_waitcnt lgkmcnt(0)" ::: "memory")
#define BARRIER()  asm volatile("s_barrier" ::: "memory")

__global__ __launch_bounds__(512, 2)
void flash_attn(__bf16* __restrict__ Qp, const __bf16* __restrict__ Kp,
                const __bf16* __restrict__ Vt, const int* __restrict__ mask)
{
    constexpr float SCALE = 0.044194173824159216f;   // 1/sqrt(512)
    constexpr int QPITCH = 520;                      // 1040 B rows: 65 slots = 1 mod 8
    constexpr int PPITCH = 264;                      // 528 B rows: 33 slots = 1 mod 8

    __shared__ __align__(16) __bf16 Qs[32 * QPITCH];  // 33280 B, linear rows
    __shared__ __align__(16) __bf16 P[32 * PPITCH];   // 16896 B, linear rows
    __shared__ float pmax[8 * 33];
    __shared__ float psum[8 * 33];

    const int bid  = blockIdx.x;
    const int n    = bid & 3;            // batch -> XCD-local K/V
    const int q0   = (bid >> 2) * 32;
    const int tid  = threadIdx.x;
    const int w    = tid >> 6;
    const int lane = tid & 63;
    const int l32  = lane & 31;
    const int half = lane >> 5;

    const __bf16* Qb = Qp + (size_t)n * SEQ * DIM;
    const __bf16* Kb = Kp + (size_t)n * SEQ * DIM;
    const __bf16* Vb = Vt + (size_t)n * DIM * SEQ;
    const int*    Mb = mask + (size_t)n * SEQ * SEQ;
    __bf16*       AO = Qp + (size_t)n * SEQ * DIM;   // alias; rows consumed first

    // ---- stage Q ONCE, linear (pitch rotation handles banks): 32 rows
    #pragma unroll
    for (int i = 0; i < 4; i++) {
        const int r = i * 8 + w;
        glds16(Qb + (size_t)(q0 + r) * DIM + lane * 8, &Qs[r * QPITCH]);
    }

    // per-lane K/V row pointers (A-frag rows: K kc=32w+l32, V d=32w+l32)
    const __bf16* kPtr  = Kb + (size_t)(32 * w + l32) * DIM + half * 8;
    const __bf16* vPtr0 = Vb + (size_t)(32 * w + l32) * SEQ + half * 8;
    const __bf16* vPtr1 = vPtr0 + (size_t)256 * SEQ;

    const int qrow0 = l32 * QPITCH;

    float m0 = -__builtin_inff();
    float l0 = 0.f;
    f32x16 o00 = {}, o10 = {};           // [h], single q-half (32 rows)
    f32x16 s0;

    bf16x8 kA[4], kB[4], vA[4], vB[4];

#define LOADKB(buf, base, dc_) { _Pragma("unroll") \
    for (int ks = 0; ks < 4; ks++) \
        buf[ks] = *(const bf16x8*)((base) + (dc_) * 64 + ks * 16); }

#define LOADV(buf, vc_) { const __bf16* vp_ = ((vc_) < 4) ? vPtr0 : vPtr1; \
    _Pragma("unroll") \
    for (int ks = 0; ks < 4; ks++) \
        buf[ks] = *(const bf16x8*)(vp_ + ((vc_) & 3) * 64 + ks * 16); }

#define QK8(buf, dc_) { __builtin_amdgcn_s_setprio(1); \
    _Pragma("unroll") \
    for (int ks = 0; ks < 4; ks++) { \
        bf16x8 b0 = *(const bf16x8*)&Qs[qrow0 + (dc_) * 64 + (2 * ks + half) * 8]; \
        s0 = MFMA32(buf[ks], b0, s0); \
    } __builtin_amdgcn_s_setprio(0); }

#define PV8(buf, vc_) { __builtin_amdgcn_s_setprio(1); \
    _Pragma("unroll") \
    for (int ks = 0; ks < 4; ks++) { \
        const int ck = ((vc_) & 3) * 8 + 2 * ks + half; \
        bf16x8 b0 = *(const bf16x8*)&P[l32 * PPITCH + ck * 8]; \
        if ((vc_) < 4) { o00 = MFMA32(buf[ks], b0, o00); } \
        else           { o10 = MFMA32(buf[ks], b0, o10); } \
    } __builtin_amdgcn_s_setprio(0); }

    __syncthreads();            // Q staged (drains the glds16 vmcnt)
    LOADKB(kA, kPtr, 0);        // j=0 chunks 0,1
    LOADKB(kB, kPtr, 1);

    #pragma unroll 1
    for (int j = 0; j < 16; j++) {
        const int k0 = j * 256;

        // ---- mask in C-fragment layout: lane (w,l32,half) covers
        // kc = 32w + 8g + 4*half + r4 for q = l32
        int4 mk0[4];
        {
            const int* mp0 = Mb + (size_t)(q0 + l32) * SEQ + k0 + 32 * w + 4 * half;
            #pragma unroll
            for (int g = 0; g < 4; g++) mk0[g] = *(const int4*)(mp0 + 8 * g);
        }

        // ---- phase 1: S^T. 2-buffer reg prefetch; V 0,1 issued at tail.
        s0 = (f32x16){};
        QK8(kA, 0); LOADKB(kA, kPtr, 2);
        QK8(kB, 1); LOADKB(kB, kPtr, 3);
        QK8(kA, 2); LOADKB(kA, kPtr, 4);
        QK8(kB, 3); LOADKB(kB, kPtr, 5);
        QK8(kA, 4); LOADKB(kA, kPtr, 6);
        QK8(kB, 5); LOADKB(kB, kPtr, 7);
        QK8(kA, 6); LOADV(vA, 0);
        QK8(kB, 7); LOADV(vB, 1);

        // ---- per-lane partial max over this wave's 32 kcols (raw scores)
        {
            float mx0 = s0[0];
            #pragma unroll
            for (int r = 1; r < 16; r++) mx0 = fmaxf(mx0, s0[r]);
            mx0 = fmaxf(mx0, __shfl_xor(mx0, 32));
            if (half == 0) pmax[w * 33 + l32] = mx0;
        }
        WAITLGKM();
        BARRIER();              // A: pmax visible

        // ---- combine max; per-lane softmax state for q = l32
        float mp0v = pmax[l32];
        #pragma unroll
        for (int w2 = 1; w2 < 8; w2++) mp0v = fmaxf(mp0v, pmax[w2 * 33 + l32]);
        const float mn0 = fmaxf(m0, mp0v * SCALE);
        const float a0 = __expf(m0 - mn0);
        m0 = mn0;
        #pragma unroll
        for (int r = 0; r < 16; r++) { o00[r] *= a0; o10[r] *= a0; }

        // ---- exp + register-mask + vectorized P write + partial lsum
        float ls0 = 0.f;
        #pragma unroll
        for (int g = 0; g < 4; g++) {
            bf16x4 pv0;
            #pragma unroll
            for (int r4 = 0; r4 < 4; r4++) {
                const int r = g * 4 + r4;
                float p0 = __expf(s0[r] * SCALE - mn0);
                p0 = MKC(mk0[g], r4) ? p0 : 0.f;
                ls0 += p0;
                pv0[r4] = (__bf16)p0;
            }
            const int c = 4 * w + g;                         // kcol chunk 0..31
            *(bf16x4*)&P[l32 * PPITCH + c * 8 + 4 * half] = pv0;
        }
        ls0 += __shfl_xor(ls0, 32);
        if (half == 0) psum[w * 33 + l32] = ls0;
        WAITLGKM();
        BARRIER();              // B: P + psum visible (V loads stay in flight)

        {
            float ss0 = 0.f;
            #pragma unroll
            for (int w2 = 0; w2 < 8; w2++) ss0 += psum[w2 * 33 + l32];
            l0 = l0 * a0 + ss0;
        }

        // ---- phase 3: PV. 2-buffer; next-j K chunks 0,1 issued at tail.
        PV8(vA, 0); LOADV(vA, 2);
        PV8(vB, 1); LOADV(vB, 3);
        PV8(vA, 2); LOADV(vA, 4);
        PV8(vB, 3); LOADV(vB, 5);
        PV8(vA, 4); LOADV(vA, 6);
        PV8(vB, 5); LOADV(vB, 7);
        PV8(vA, 6); if (j < 15) LOADKB(kA, kPtr + 256 * DIM, 0);
        PV8(vB, 7); if (j < 15) LOADKB(kB, kPtr + 256 * DIM, 1);

        kPtr  += 256 * DIM;
        vPtr0 += 256;
        vPtr1 += 256;
        WAITLGKM();
        BARRIER();              // C: P safe to rewrite next j (K loads in flight)
    }

    // ---- epilogue: AO[q][d] = O^T[d][q] / l
    const float li0 = 1.f / l0;
    __bf16* ao0 = AO + (size_t)(q0 + l32) * DIM;
    #pragma unroll
    for (int h = 0; h < 2; h++) {
        #pragma unroll
        for (int g = 0; g < 4; g++) {
            bf16x4 v00;
            #pragma unroll
            for (int r4 = 0; r4 < 4; r4++) {
                const int r = g * 4 + r4;
                v00[r4] = (__bf16)((h ? o10[r] : o00[r]) * li0);
            }
            const int d = h * 256 + 32 * w + g * 8 + 4 * half;
            *(bf16x4*)&ao0[d] = v00;
        }
    }
#undef LOADKB
#undef LOADV
#undef QK8
#undef PV8
}

// ---------------------------------------------------------------------------
extern "C" void kernel_launch(void* const* d_in, const int* in_sizes, int n_in,
                              void* d_out, int out_size, void* d_ws, size_t ws_size,
                              hipStream_t stream)
{
    const float* values = (const float*)d_in[0];
    const float* keys   = (const float*)d_in[1];
    const float* query  = (const float*)d_in[2];
    const int*   mask   = (const int*)d_in[3];
    const float* Wv = (const float*)d_in[4];
    const float* Wk = (const float*)d_in[5];
    const float* Wq = (const float*)d_in[6];
    const float* Wo = (const float*)d_in[7];
    const float* bo = (const float*)d_in[8];
    float* out = (float*)d_out;

    char* ws = (char*)d_ws;
    __bf16* Qp  = (__bf16*)(ws);                 // 16 MiB (AO aliases)
    __bf16* Kp  = (__bf16*)(ws + (16u << 20));   // 16 MiB
    __bf16* Vt  = (__bf16*)(ws + (32u << 20));   // 16 MiB
    __bf16* wbf = (__bf16*)(ws + (48u << 20));   // 2 MiB

    const int M = 4 * SEQ;  // 16384

    convert_w<<<dim3(128, 4), 256, 0, stream>>>(Wq, Wk, Wv, Wo, wbf);

    // batched Q/K/V projection with fused fp32->bf16 A conversion
    gemm_qkv<<<dim3(M / 128, DIM / 128, 3), 256, 0, stream>>>(
        query, keys, values, wbf, Qp, Kp, Vt);

    flash_attn<<<512, 512, 0, stream>>>(Qp, Kp, Vt, mask);

    gemm_out<<<dim3(M / 128, DIM / 128), 256, 0, stream>>>(
        Qp /*AO*/, wbf + 3 * DIM * DIM, out, bo);
}